// Round 6
// baseline (632.811 us; speedup 1.0000x reference)
//
#include <hip/hip_runtime.h>
#include <stdint.h>

// ArcticDecoderLayer on MI355X (gfx950).
// Precision plan: f16 MFMA everywhere except (a) o-proj GEMM in f16 hi/lo split
// (3 MFMAs) because its error feeds MoE top-k routing, (b) routing itself in
// fp32, (c) RoPE phases in fp64 (table'd; matches numpy float64 promotion).
// R10: MoE GEMMs read fp32 weights DIRECTLY (kills cvt_f16 passes for ws/w2s,
// ~300 MB of streaming). B panels staged fp32 via glds16 with even-XOR seg
// swizzle (phys_seg = seg ^ ((row&3)<<1); even mask keeps 16B adjacency, caps
// read conflicts at 4-way), read as f32x4 pairs + RTN casts to f16x8 (bit-
// identical to the old cvt kernel). LDS 72 KB -> 2 blk/CU: free for down-proj
// (grid gives 2/CU anyway), small occupancy cost on up-proj < saved 32 us.
// + routing fused into rmsnorm_dual (same fp32 association order as before).
// T=2048 H=1024 NH=16 NKV=4 HD=64 I=2048 E=8 TOPK=2

typedef _Float16 f16;
typedef _Float16 f16x8 __attribute__((ext_vector_type(8)));
typedef _Float16 f16x4 __attribute__((ext_vector_type(4)));
typedef float f32x4 __attribute__((ext_vector_type(4)));

#define DEV __device__ __forceinline__

DEV void glds16(const void* g, void* l) {
  __builtin_amdgcn_global_load_lds((const __attribute__((address_space(1))) void*)g,
                                   (__attribute__((address_space(3))) void*)l, 16, 0, 0);
}

// fp32x8 (LDS) -> f16x8, RTN scalar casts (matches cvt kernel rounding)
DEV f16x8 cvt8(const float* p) {
  f32x4 lo = *(const f32x4*)p;
  f32x4 hi = *(const f32x4*)(p + 4);
  f16x8 o;
  o[0] = (f16)lo[0]; o[1] = (f16)lo[1]; o[2] = (f16)lo[2]; o[3] = (f16)lo[3];
  o[4] = (f16)hi[0]; o[5] = (f16)hi[1]; o[6] = (f16)hi[2]; o[7] = (f16)hi[3];
  return o;
}

// ---------------- conversions ----------------
__global__ void cvt_f16_kernel(const float* __restrict__ in, f16* __restrict__ outp) {
  const size_t i = ((size_t)blockIdx.x * 256 + threadIdx.x) * 4;
  float4 f = *(const float4*)(in + i);
  f16x4 o;
  o[0] = (f16)f.x; o[1] = (f16)f.y; o[2] = (f16)f.z; o[3] = (f16)f.w;
  *(f16x4*)(outp + i) = o;
}

__global__ void cvt_f16x2_kernel(const float* __restrict__ in,
                                 f16* __restrict__ oh, f16* __restrict__ ol) {
  const size_t i = ((size_t)blockIdx.x * 256 + threadIdx.x) * 4;
  float4 f = *(const float4*)(in + i);
  f16x4 h, l;
  h[0] = (f16)f.x; l[0] = (f16)(f.x - (float)h[0]);
  h[1] = (f16)f.y; l[1] = (f16)(f.y - (float)h[1]);
  h[2] = (f16)f.z; l[2] = (f16)(f.z - (float)h[2]);
  h[3] = (f16)f.w; l[3] = (f16)(f.w - (float)h[3]);
  *(f16x4*)(oh + i) = h;
  *(f16x4*)(ol + i) = l;
}

// ---------------- RMS norm (wave per row, 1024 cols) ----------------
__global__ void rmsnorm_kernel(const float* __restrict__ in, const float* __restrict__ w,
                               f16* __restrict__ outp) {
  const int t = blockIdx.x * 4 + (threadIdx.x >> 6);
  const int lane = threadIdx.x & 63;
  const float* x = in + (size_t)t * 1024;
  float v[16]; float ss = 0.f;
#pragma unroll
  for (int j = 0; j < 16; j++) { float a = x[lane + 64 * j]; v[j] = a; ss += a * a; }
#pragma unroll
  for (int m = 1; m < 64; m <<= 1) ss += __shfl_xor(ss, m);
  const float rs = rsqrtf(ss * (1.f / 1024.f) + 1e-5f);
#pragma unroll
  for (int j = 0; j < 16; j++)
    outp[(size_t)t * 1024 + lane + 64 * j] = (f16)(v[j] * rs * w[lane + 64 * j]);
}

// ---------------- fused dual RMS norm + MoE routing ----------------
// o1 = rmsnorm(in)*w1 (f16), o2 = rmsnorm(in)*w2 (f16); routing logits from
// the fp32 postw-scaled values with the SAME association order as the old
// routing kernel (v * (rs*w2)) to preserve top-2 tie behavior.
__global__ void rmsnorm_dual_route_kernel(
    const float* __restrict__ in, const float* __restrict__ w1, const float* __restrict__ w2,
    const float* __restrict__ gw, f16* __restrict__ o1, f16* __restrict__ o2,
    int* __restrict__ counts, int* __restrict__ perm, float* __restrict__ rw) {
  const int t = blockIdx.x * 4 + (threadIdx.x >> 6);
  const int lane = threadIdx.x & 63;
  const float* x = in + (size_t)t * 1024;
  float v[16]; float ss = 0.f;
#pragma unroll
  for (int j = 0; j < 16; j++) { float a = x[lane + 64 * j]; v[j] = a; ss += a * a; }
#pragma unroll
  for (int m = 1; m < 64; m <<= 1) ss += __shfl_xor(ss, m);
  const float rs = rsqrtf(ss * (1.f / 1024.f) + 1e-5f);
  float pv[16];
#pragma unroll
  for (int j = 0; j < 16; j++) {
    const float w1j = w1[lane + 64 * j], w2j = w2[lane + 64 * j];
    const float nv = v[j] * rs;
    size_t idx = (size_t)t * 1024 + lane + 64 * j;
    o1[idx] = (f16)(nv * w1j);
    o2[idx] = (f16)(nv * w2j);
    pv[j] = v[j] * (rs * w2j);  // routing-precision order (matches old kernel)
  }
  float lg[8];
#pragma unroll
  for (int e = 0; e < 8; e++) {
    float p = 0.f;
    const float* g = gw + (size_t)e * 1024;
#pragma unroll
    for (int j = 0; j < 16; j++) p += pv[j] * g[lane + 64 * j];
#pragma unroll
    for (int m = 1; m < 64; m <<= 1) p += __shfl_xor(p, m);
    lg[e] = p;
  }
  if (lane == 0) {
    int e0 = 0; float b0 = lg[0];
#pragma unroll
    for (int e = 1; e < 8; e++) if (lg[e] > b0) { b0 = lg[e]; e0 = e; }
    int e1 = -1; float b1 = -3e38f;
#pragma unroll
    for (int e = 0; e < 8; e++) if (e != e0 && lg[e] > b1) { b1 = lg[e]; e1 = e; }
    const float w0 = 1.f / (1.f + expf(b1 - b0));  // p0/(p0+p1)
    const float wq = 1.f - w0;
    int p0 = atomicAdd(&counts[e0], 1);
    perm[e0 * 2048 + p0] = t * 2;
    int p1 = atomicAdd(&counts[e1], 1);
    perm[e1 * 2048 + p1] = t * 2 + 1;
    rw[t * 2] = w0;
    rw[t * 2 + 1] = wq;
  }
}

// ---------------- main GEMM: C[M,N] = A[M,K] * B[N,K]^T, 128xBN x32 tiles ----
// 3-buffer counted-vmcnt pipeline: wait own stage(t) (vmcnt(L), stage(t+1)
// stays in flight), barrier, issue stage(t+2) into buf[(t-1)%3], compute t.
// EPI: 0 = fp32 store, 1 = fp32 store + addsrc, 2 = f16 store
template <int EPI, int BN, int SPLITK = 1>
__global__ __launch_bounds__(256) void gemm_f16_kernel(
    const f16* __restrict__ A, const f16* __restrict__ B,
    void* __restrict__ outp, const float* __restrict__ addsrc,
    int M, int N, int K) {
  constexpr int JT = BN / 32;  // col fragments per wave (wave covers BN/2 cols)
  constexpr int L = (BN == 128) ? 4 : 3;  // glds per thread per K-tile
  __shared__ __attribute__((aligned(16))) f16 As[3][128 * 32];
  __shared__ __attribute__((aligned(16))) f16 Bs[3][BN * 32];
  const int tid = threadIdx.x;
  const size_t row0 = (size_t)blockIdx.y * 128, col0 = (size_t)blockIdx.x * BN;
  const int ks = (SPLITK > 1) ? (int)blockIdx.z : 0;
  const int kspan = K / SPLITK, kb = ks * kspan;
  const int nt = kspan >> 5;
  const int c0 = tid, c1 = tid + 256;
  // pre-swizzled global k-segment: phys seg (tid&3) holds logical seg ^((row>>1)&3)
  const int sw0 = ((c0 & 3) ^ ((c0 >> 3) & 3)) * 8;
  const int sw1 = ((c1 & 3) ^ ((c1 >> 3) & 3)) * 8;
  const f16* a0 = A + (row0 + (c0 >> 2)) * K + sw0;
  const f16* a1 = A + (row0 + (c1 >> 2)) * K + sw1;
  const f16* b0 = B + (col0 + (c0 >> 2)) * K + sw0;
  const f16* b1 = B + (col0 + ((BN == 128) ? (c1 >> 2) : 0)) * K + ((BN == 128) ? sw1 : 0);

  const int wave = tid >> 6, lane = tid & 63, lr = lane >> 4, lc = lane & 15;
  const int wr = wave >> 1, wc = wave & 1;
  const int rsw = (lr ^ ((lc >> 1) & 3)) * 8;  // swizzled read k-offset

  f32x4 acc[4][JT];
#pragma unroll
  for (int i = 0; i < 4; i++)
#pragma unroll
    for (int j = 0; j < JT; j++) acc[i][j] = (f32x4){0.f, 0.f, 0.f, 0.f};

  auto stage = [&](int k0, int buf) {
    glds16(a0 + k0, As[buf] + c0 * 8);
    glds16(a1 + k0, As[buf] + c1 * 8);
    glds16(b0 + k0, Bs[buf] + c0 * 8);
    if constexpr (BN == 128) glds16(b1 + k0, Bs[buf] + c1 * 8);
  };

  stage(kb, 0); stage(kb + 32, 1);
  for (int t = 0; t < nt; ++t) {
    if (t < nt - 1) asm volatile("s_waitcnt vmcnt(%0)" :: "n"(L) : "memory");
    else            asm volatile("s_waitcnt vmcnt(0)" ::: "memory");
    __builtin_amdgcn_s_barrier();
    asm volatile("" ::: "memory");
    if (t + 2 < nt) stage(kb + (t + 2) * 32, (t + 2) % 3);
    const f16* Ab = As[t % 3];
    const f16* Bb = Bs[t % 3];
    f16x8 af[4], bfr[JT];
#pragma unroll
    for (int i = 0; i < 4; i++)
      af[i] = *(const f16x8*)(Ab + (wr * 64 + i * 16 + lc) * 32 + rsw);
#pragma unroll
    for (int j = 0; j < JT; j++)
      bfr[j] = *(const f16x8*)(Bb + (wc * (BN / 2) + j * 16 + lc) * 32 + rsw);
#pragma unroll
    for (int i = 0; i < 4; i++)
#pragma unroll
      for (int j = 0; j < JT; j++)
        acc[i][j] = __builtin_amdgcn_mfma_f32_16x16x32_f16(af[i], bfr[j], acc[i][j], 0, 0, 0);
  }

#pragma unroll
  for (int i = 0; i < 4; i++)
#pragma unroll
    for (int j = 0; j < JT; j++) {
      const size_t rbase = row0 + wr * 64 + i * 16 + lr * 4;
      const size_t col = col0 + wc * (BN / 2) + j * 16 + lc;
#pragma unroll
      for (int r = 0; r < 4; r++) {
        size_t idx = (rbase + r) * N + col;
        if constexpr (SPLITK > 1) {
          ((float*)outp)[(size_t)ks * M * N + idx] = acc[i][j][r];
        } else if constexpr (EPI == 0) ((float*)outp)[idx] = acc[i][j][r];
        else if constexpr (EPI == 1) ((float*)outp)[idx] = acc[i][j][r] + addsrc[idx];
        else ((f16*)outp)[idx] = (f16)acc[i][j][r];
      }
    }
}

// ---------------- o-proj GEMM, f16 hi/lo split (3 MFMAs), 128x64 ------------
// 3-buffer counted-vmcnt (72 KB LDS -> 2 blk/CU).
// SPLITK>1: fp32 partials at outp + ks*M*N (no addsrc; add3 combines).
template <int SPLITK>
__global__ __launch_bounds__(256) void gemm_f16x2_add_kernel(
    const f16* __restrict__ Ah, const f16* __restrict__ Al,
    const f16* __restrict__ Bh, const f16* __restrict__ Bl,
    float* __restrict__ outp, const float* __restrict__ addsrc,
    int M, int N, int K) {
  __shared__ __attribute__((aligned(16))) f16 Ash[3][128 * 32];
  __shared__ __attribute__((aligned(16))) f16 Asl[3][128 * 32];
  __shared__ __attribute__((aligned(16))) f16 Bsh[3][64 * 32];
  __shared__ __attribute__((aligned(16))) f16 Bsl[3][64 * 32];
  const int tid = threadIdx.x;
  const size_t row0 = (size_t)blockIdx.y * 128, col0 = (size_t)blockIdx.x * 64;
  const int ks = (SPLITK > 1) ? (int)blockIdx.z : 0;
  const int kspan = K / SPLITK, kb = ks * kspan;
  const int nt = kspan >> 5;
  const int c0 = tid, c1 = tid + 256;
  const int sw0 = ((c0 & 3) ^ ((c0 >> 3) & 3)) * 8;
  const int sw1 = ((c1 & 3) ^ ((c1 >> 3) & 3)) * 8;
  const size_t aoff0 = (row0 + (c0 >> 2)) * K + sw0;
  const size_t aoff1 = (row0 + (c1 >> 2)) * K + sw1;
  const size_t boff0 = (col0 + (c0 >> 2)) * K + sw0;

  const int wave = tid >> 6, lane = tid & 63, lr = lane >> 4, lc = lane & 15;
  const int wr = wave >> 1, wc = wave & 1;
  const int rsw = (lr ^ ((lc >> 1) & 3)) * 8;

  f32x4 acc[4][2];
#pragma unroll
  for (int i = 0; i < 4; i++)
#pragma unroll
    for (int j = 0; j < 2; j++) acc[i][j] = (f32x4){0.f, 0.f, 0.f, 0.f};

  auto stage = [&](int k0, int buf) {
    glds16(Ah + aoff0 + k0, Ash[buf] + c0 * 8);
    glds16(Ah + aoff1 + k0, Ash[buf] + c1 * 8);
    glds16(Al + aoff0 + k0, Asl[buf] + c0 * 8);
    glds16(Al + aoff1 + k0, Asl[buf] + c1 * 8);
    glds16(Bh + boff0 + k0, Bsh[buf] + c0 * 8);
    glds16(Bl + boff0 + k0, Bsl[buf] + c0 * 8);
  };

  stage(kb, 0); stage(kb + 32, 1);
  for (int t = 0; t < nt; ++t) {
    if (t < nt - 1) asm volatile("s_waitcnt vmcnt(%0)" :: "n"(6) : "memory");
    else            asm volatile("s_waitcnt vmcnt(0)" ::: "memory");
    __builtin_amdgcn_s_barrier();
    asm volatile("" ::: "memory");
    if (t + 2 < nt) stage(kb + (t + 2) * 32, (t + 2) % 3);
    const int bc = t % 3;
    f16x8 afh[4], afl[4], bfh[2], bfl[2];
#pragma unroll
    for (int i = 0; i < 4; i++) {
      const int ro = (wr * 64 + i * 16 + lc) * 32 + rsw;
      afh[i] = *(const f16x8*)(Ash[bc] + ro);
      afl[i] = *(const f16x8*)(Asl[bc] + ro);
    }
#pragma unroll
    for (int j = 0; j < 2; j++) {
      const int ro = (wc * 32 + j * 16 + lc) * 32 + rsw;
      bfh[j] = *(const f16x8*)(Bsh[bc] + ro);
      bfl[j] = *(const f16x8*)(Bsl[bc] + ro);
    }
#pragma unroll
    for (int i = 0; i < 4; i++)
#pragma unroll
      for (int j = 0; j < 2; j++) {
        acc[i][j] = __builtin_amdgcn_mfma_f32_16x16x32_f16(afh[i], bfh[j], acc[i][j], 0, 0, 0);
        acc[i][j] = __builtin_amdgcn_mfma_f32_16x16x32_f16(afh[i], bfl[j], acc[i][j], 0, 0, 0);
        acc[i][j] = __builtin_amdgcn_mfma_f32_16x16x32_f16(afl[i], bfh[j], acc[i][j], 0, 0, 0);
      }
  }

#pragma unroll
  for (int i = 0; i < 4; i++)
#pragma unroll
    for (int j = 0; j < 2; j++) {
      const size_t rbase = row0 + wr * 64 + i * 16 + lr * 4;
      const size_t col = col0 + wc * 32 + j * 16 + lc;
#pragma unroll
      for (int r = 0; r < 4; r++) {
        size_t idx = (rbase + r) * N + col;
        if constexpr (SPLITK > 1) outp[(size_t)ks * M * N + idx] = acc[i][j][r];
        else outp[idx] = acc[i][j][r] + addsrc[idx];
      }
    }
}

// ---------------- gated MoE up-proj, fp32 weights -----------------
// actm[sid] = silu(A*Bg^T) * (A*Bu^T); Bg = ws rows [col0,+64), Bu = rows
// [2048+col0,+64) read DIRECTLY from fp32 ws via glds16 with even-XOR seg
// swizzle (phys = seg ^ ((row&3)<<1)); read as f32x4 pairs + RTN cast.
// LDS 3*(8+8+8)=72 KB. 6 glds/thread/K-step -> vmcnt(6).
__global__ __launch_bounds__(256) void gemm_moe_gated_kernel(
    const f16* __restrict__ A, const float* __restrict__ Ball, f16* __restrict__ actm,
    const int* __restrict__ perm, const int* __restrict__ counts,
    int K, size_t strideB) {
  const int e = (int)blockIdx.z;
  const int cnt = counts[e];
  const int bm = blockIdx.y;
  if (bm * 128 >= cnt) return;
  const int nt = K >> 5;
  const float* B = Ball + (size_t)e * strideB;
  __shared__ __attribute__((aligned(16))) f16 As[3][128 * 32];
  __shared__ __attribute__((aligned(16))) float Bgs[3][64 * 32];
  __shared__ __attribute__((aligned(16))) float Bus[3][64 * 32];
  const int tid = threadIdx.x;
  const size_t col0 = (size_t)blockIdx.x * 64;
  const int c0 = tid, c1 = tid + 256;
  const int pbase = e * 2048 + bm * 128;
  const int rt0 = c0 >> 2, rt1 = c1 >> 2;
  const int sid0 = (bm * 128 + rt0 < cnt) ? perm[pbase + rt0] : 0;
  const int sid1 = (bm * 128 + rt1 < cnt) ? perm[pbase + rt1] : 0;
  const size_t ar0 = (size_t)(sid0 >> 1);  // token row
  const size_t ar1 = (size_t)(sid1 >> 1);
  const int sw0 = ((c0 & 3) ^ ((c0 >> 3) & 3)) * 8;
  const int sw1 = ((c1 & 3) ^ ((c1 >> 3) & 3)) * 8;
  const f16* ap0 = A + ar0 * K + sw0;
  const f16* ap1 = A + ar1 * K + sw1;
  // fp32 B slots: slot c covers row c>>3, phys seg c&7; rows c and c+256 share
  // (row&3) so one source seg sB serves both.
  const int rB = c0 >> 3;
  const int sB = (c0 & 7) ^ ((rB & 3) << 1);
  const float* bg0 = B + (size_t)(col0 + rB) * K + sB * 4;
  const float* bu0 = B + (size_t)(2048 + col0 + rB) * K + sB * 4;

  const int wave = tid >> 6, lane = tid & 63, lr = lane >> 4, lc = lane & 15;
  const int wr = wave >> 1, wc = wave & 1;
  const int rsw = (lr ^ ((lc >> 1) & 3)) * 8;

  f32x4 accg[4][2], accu[4][2];
#pragma unroll
  for (int i = 0; i < 4; i++)
#pragma unroll
    for (int j = 0; j < 2; j++) {
      accg[i][j] = (f32x4){0.f, 0.f, 0.f, 0.f};
      accu[i][j] = (f32x4){0.f, 0.f, 0.f, 0.f};
    }

  auto stage = [&](int k0, int buf) {
    glds16(ap0 + k0, As[buf] + c0 * 8);
    glds16(ap1 + k0, As[buf] + c1 * 8);
    glds16(bg0 + k0, Bgs[buf] + c0 * 4);
    glds16(bg0 + (size_t)32 * K + k0, Bgs[buf] + (c0 + 256) * 4);
    glds16(bu0 + k0, Bus[buf] + c0 * 4);
    glds16(bu0 + (size_t)32 * K + k0, Bus[buf] + (c0 + 256) * 4);
  };

  stage(0, 0); stage(32, 1);
  for (int t = 0; t < nt; ++t) {
    if (t < nt - 1) asm volatile("s_waitcnt vmcnt(%0)" :: "n"(6) : "memory");
    else            asm volatile("s_waitcnt vmcnt(0)" ::: "memory");
    __builtin_amdgcn_s_barrier();
    asm volatile("" ::: "memory");
    if (t + 2 < nt) stage((t + 2) * 32, (t + 2) % 3);
    const f16* Ab = As[t % 3];
    const float* Bgb = Bgs[t % 3];
    const float* Bub = Bus[t % 3];
    f16x8 af[4], bg[2], bu[2];
#pragma unroll
    for (int i = 0; i < 4; i++)
      af[i] = *(const f16x8*)(Ab + (wr * 64 + i * 16 + lc) * 32 + rsw);
#pragma unroll
    for (int j = 0; j < 2; j++) {
      const int rb = wc * 32 + j * 16 + lc;
      const int po = ((2 * lr) ^ ((rb & 3) << 1)) * 4;
      bg[j] = cvt8(Bgb + rb * 32 + po);
      bu[j] = cvt8(Bub + rb * 32 + po);
    }
    __builtin_amdgcn_s_setprio(1);
#pragma unroll
    for (int i = 0; i < 4; i++)
#pragma unroll
      for (int j = 0; j < 2; j++) {
        accg[i][j] = __builtin_amdgcn_mfma_f32_16x16x32_f16(af[i], bg[j], accg[i][j], 0, 0, 0);
        accu[i][j] = __builtin_amdgcn_mfma_f32_16x16x32_f16(af[i], bu[j], accu[i][j], 0, 0, 0);
      }
    __builtin_amdgcn_s_setprio(0);
  }

  int sids[4][4];
#pragma unroll
  for (int i = 0; i < 4; i++)
#pragma unroll
    for (int r = 0; r < 4; r++) {
      int rit = wr * 64 + i * 16 + lr * 4 + r;
      sids[i][r] = (bm * 128 + rit < cnt) ? perm[pbase + rit] : -1;
    }
#pragma unroll
  for (int i = 0; i < 4; i++)
#pragma unroll
    for (int j = 0; j < 2; j++) {
      const size_t col = col0 + wc * 32 + j * 16 + lc;
#pragma unroll
      for (int r = 0; r < 4; r++)
        if (sids[i][r] >= 0) {
          const float g = accg[i][j][r], u = accu[i][j][r];
          actm[(size_t)sids[i][r] * 2048 + col] = (f16)(g / (1.f + __expf(-g)) * u);
        }
    }
}

// ---------------- MoE down-proj, fp32 weights, SPLITK=2 -----------------
// A = actm (f16, slot rows); B = w2s fp32 staged via glds16 (128x32 fp32 =
// 16 KB/buffer, 4 glds/thread) with the same even-XOR seg swizzle.
// LDS 3*(8+16)=72 KB -> 2 blk/CU (== available work). vmcnt(6).
__global__ __launch_bounds__(256) void gemm_moe_down_kernel(
    const f16* __restrict__ A, const float* __restrict__ Ball, float* __restrict__ outp,
    const int* __restrict__ perm, const int* __restrict__ counts,
    int N, int K, size_t strideB) {
  constexpr int SPLITK = 2;
  const int e = (int)blockIdx.z / SPLITK;
  const int ks = (int)blockIdx.z % SPLITK;
  const int cnt = counts[e];
  const int bm = blockIdx.y;
  if (bm * 128 >= cnt) return;
  const int kspan = K / SPLITK, kb = ks * kspan;
  const int nt = kspan >> 5;
  const float* B = Ball + (size_t)e * strideB;
  __shared__ __attribute__((aligned(16))) f16 As[3][128 * 32];
  __shared__ __attribute__((aligned(16))) float Bs[3][128 * 32];
  const int tid = threadIdx.x;
  const size_t col0 = (size_t)blockIdx.x * 128;
  const int c0 = tid, c1 = tid + 256;
  const int pbase = e * 2048 + bm * 128;
  const int rt0 = c0 >> 2, rt1 = c1 >> 2;
  const int sid0 = (bm * 128 + rt0 < cnt) ? perm[pbase + rt0] : 0;
  const int sid1 = (bm * 128 + rt1 < cnt) ? perm[pbase + rt1] : 0;
  const size_t ar0 = (size_t)sid0;  // slot row
  const size_t ar1 = (size_t)sid1;
  const int sw0 = ((c0 & 3) ^ ((c0 >> 3) & 3)) * 8;
  const int sw1 = ((c1 & 3) ^ ((c1 >> 3) & 3)) * 8;
  const f16* ap0 = A + ar0 * K + sw0;
  const f16* ap1 = A + ar1 * K + sw1;
  const int rB = c0 >> 3;  // rows rB, rB+32, rB+64, rB+96 share (row&3)
  const int sB = (c0 & 7) ^ ((rB & 3) << 1);
  const float* b0 = B + (size_t)(col0 + rB) * K + sB * 4;

  const int wave = tid >> 6, lane = tid & 63, lr = lane >> 4, lc = lane & 15;
  const int wr = wave >> 1, wc = wave & 1;
  const int rsw = (lr ^ ((lc >> 1) & 3)) * 8;

  f32x4 acc[4][4];
#pragma unroll
  for (int i = 0; i < 4; i++)
#pragma unroll
    for (int j = 0; j < 4; j++) acc[i][j] = (f32x4){0.f, 0.f, 0.f, 0.f};

  auto stage = [&](int k0, int buf) {
    glds16(ap0 + k0, As[buf] + c0 * 8);
    glds16(ap1 + k0, As[buf] + c1 * 8);
    glds16(b0 + k0, Bs[buf] + c0 * 4);
    glds16(b0 + (size_t)32 * K + k0, Bs[buf] + (c0 + 256) * 4);
    glds16(b0 + (size_t)64 * K + k0, Bs[buf] + (c0 + 512) * 4);
    glds16(b0 + (size_t)96 * K + k0, Bs[buf] + (c0 + 768) * 4);
  };

  stage(kb, 0); stage(kb + 32, 1);
  for (int t = 0; t < nt; ++t) {
    if (t < nt - 1) asm volatile("s_waitcnt vmcnt(%0)" :: "n"(6) : "memory");
    else            asm volatile("s_waitcnt vmcnt(0)" ::: "memory");
    __builtin_amdgcn_s_barrier();
    asm volatile("" ::: "memory");
    if (t + 2 < nt) stage(kb + (t + 2) * 32, (t + 2) % 3);
    const f16* Ab = As[t % 3];
    const float* Bb = Bs[t % 3];
    f16x8 af[4], bfr[4];
#pragma unroll
    for (int i = 0; i < 4; i++)
      af[i] = *(const f16x8*)(Ab + (wr * 64 + i * 16 + lc) * 32 + rsw);
#pragma unroll
    for (int j = 0; j < 4; j++) {
      const int rb = wc * 64 + j * 16 + lc;
      const int po = ((2 * lr) ^ ((rb & 3) << 1)) * 4;
      bfr[j] = cvt8(Bb + rb * 32 + po);
    }
    __builtin_amdgcn_s_setprio(1);
#pragma unroll
    for (int i = 0; i < 4; i++)
#pragma unroll
      for (int j = 0; j < 4; j++)
        acc[i][j] = __builtin_amdgcn_mfma_f32_16x16x32_f16(af[i], bfr[j], acc[i][j], 0, 0, 0);
    __builtin_amdgcn_s_setprio(0);
  }

  int sids[4][4];
#pragma unroll
  for (int i = 0; i < 4; i++)
#pragma unroll
    for (int r = 0; r < 4; r++) {
      int rit = wr * 64 + i * 16 + lr * 4 + r;
      sids[i][r] = (bm * 128 + rit < cnt) ? perm[pbase + rit] : -1;
    }
#pragma unroll
  for (int i = 0; i < 4; i++)
#pragma unroll
    for (int j = 0; j < 4; j++) {
      const size_t col = col0 + wc * 64 + j * 16 + lc;
#pragma unroll
      for (int r = 0; r < 4; r++)
        if (sids[i][r] >= 0)
          outp[((size_t)ks * 4096 + sids[i][r]) * N + col] = acc[i][j][r];
    }
}

// ---------------- RoPE phase table: (t,i) -> (cos,sin), fp64 once -----------
__global__ void rope_table_kernel(const int* __restrict__ pos, float2* __restrict__ tab) {
  const int idx = blockIdx.x * 256 + threadIdx.x;  // 0..65535
  const int t = idx >> 5, i = idx & 31;
  const double ph = (double)pos[t] * exp((double)i * -0.28782313662425575);  // ln(1e4)/32
  tab[idx] = make_float2((float)cos(ph), (float)sin(ph));
}

// ---------------- RoPE: table lookup, reads qkv split partials (sum) --------
__global__ void rope_kernel(const float* __restrict__ qkv, const float2* __restrict__ tab,
                            f16* __restrict__ qr, f16* __restrict__ kr) {
  const int t = blockIdx.y;
  const int u = blockIdx.x * 256 + threadIdx.x;  // 0..767, use 0..639
  if (u >= 640) return;
  const float* b0 = qkv + (size_t)t * 1536;
  const float* b1 = b0 + (size_t)2048 * 1536;
  const int head = u >> 5, i = u & 31;
  const bool isq = head < 16;
  const int off = isq ? head * 64 + i : 1024 + (head - 16) * 64 + i;
  const float x1 = b0[off] + b1[off], x2 = b0[off + 32] + b1[off + 32];
  const float2 cs = tab[t * 32 + i];
  const float c = cs.x, s = cs.y;
  const float r1 = x1 * c - x2 * s, r2 = x2 * c + x1 * s;
  if (isq) {
    // 0.125 * log2(e): base-2 softmax in attn
    const float qs = 0.18033688011116042f;
    qr[(size_t)t * 1024 + head * 64 + i] = (f16)(qs * r1);
    qr[(size_t)t * 1024 + head * 64 + i + 32] = (f16)(qs * r2);
  } else {
    const int kh = head - 16;
    kr[(size_t)t * 256 + kh * 64 + i] = (f16)r1;
    kr[(size_t)t * 256 + kh * 64 + i + 32] = (f16)r2;
  }
}

// ---------------- V transpose from qkv split partials (sum) -----------------
__global__ void vtrans_kernel(const float* __restrict__ qkvf, f16* __restrict__ vt) {
  __shared__ float Ts[64 * 69];
  const int t0 = blockIdx.x * 64;
  const int kv = blockIdx.y;
  const int tid = threadIdx.x;
  const int tr = tid >> 2, jj = tid & 3;
  const float* src0 = qkvf + (size_t)(t0 + tr) * 1536 + 1280 + kv * 64 + jj * 16;
  const float* src1 = src0 + (size_t)2048 * 1536;
#pragma unroll
  for (int x = 0; x < 4; x++) {
    float4 f = *(const float4*)(src0 + x * 4);
    float4 g = *(const float4*)(src1 + x * 4);
    Ts[tr * 69 + jj * 16 + x * 4 + 0] = f.x + g.x;
    Ts[tr * 69 + jj * 16 + x * 4 + 1] = f.y + g.y;
    Ts[tr * 69 + jj * 16 + x * 4 + 2] = f.z + g.z;
    Ts[tr * 69 + jj * 16 + x * 4 + 3] = f.w + g.w;
  }
  __syncthreads();
  f16* dst = vt + (size_t)(kv * 64 + tr) * 2048 + t0 + jj * 16;
#pragma unroll
  for (int x = 0; x < 2; x++) {
    f16x8 o;
#pragma unroll
    for (int i = 0; i < 8; i++) o[i] = (f16)Ts[(jj * 16 + x * 8 + i) * 69 + tr];
    *(f16x8*)(dst + x * 8) = o;
  }
}

// ---------------- add3: o = a + p0 + p1 (fp32, deterministic combine) -------
__global__ void add3_kernel(float* __restrict__ o, const float* __restrict__ a,
                            const float* __restrict__ p0, const float* __restrict__ p1) {
  const size_t i4 = ((size_t)blockIdx.x * 256 + threadIdx.x) * 4;
  float4 va = *(const float4*)(a + i4);
  float4 v0 = *(const float4*)(p0 + i4);
  float4 v1 = *(const float4*)(p1 + i4);
  va.x += v0.x + v1.x;
  va.y += v0.y + v1.y;
  va.z += v0.z + v1.z;
  va.w += v0.w + v1.w;
  *(float4*)(o + i4) = va;
}

// ---------------- flash attention v4: S^T = K*Q^T + LDS-staged K/V ----------
// 4 waves/block, each wave 16 q-rows (block = 64). K,V^T staged per 128-chunk
// into padded LDS (stride 72 / 136 f16 -> conflict-free b128 access). Next-chunk
// global loads prefetched into VGPRs during compute. 52 KB LDS -> 3 blk/CU.
__global__ __launch_bounds__(256, 3) void attn_kernel(
    const f16* __restrict__ qr, const f16* __restrict__ kr, const f16* __restrict__ vt,
    f16* __restrict__ ahi, f16* __restrict__ alo) {
  const int qt = 31 - (int)blockIdx.x;  // 64-row q tiles, heavy first
  const int h = blockIdx.y;
  const int kvh = h >> 2;
  __shared__ __attribute__((aligned(16))) f16 Ks[128 * 72];   // [k=128][d=64 +8pad]
  __shared__ __attribute__((aligned(16))) f16 Vs[64 * 136];   // [d=64][k=128 +8pad]
  __shared__ __attribute__((aligned(16))) f16 Pl[4 * 16 * 136];  // per-wave P^T strips
  const int tid = threadIdx.x;
  const int wave = tid >> 6, lane = tid & 63, lr = lane >> 4, lc = lane & 15;
  const int trow = qt * 64 + wave * 16 + lc;  // this lane's q row (S^T column)
  f16* Pw = Pl + wave * 16 * 136;

  // staging roles (whole block)
  const int krow = tid >> 3, kcol = (tid & 7) * 8;    // 32 k-rows per iter, 4 iters
  const int vrow = tid >> 4, vcol = (tid & 15) * 8;   // 16 d-rows per iter, 4 iters
  const f16* kgbase = kr + (size_t)kvh * 64 + kcol;
  const f16* vgbase = vt + (size_t)(kvh * 64 + vrow) * 2048 + vcol;

  // Q as B-operand: B[n=lc=t][k=d]
  const f16* qp = qr + (size_t)trow * 1024 + h * 64 + lr * 8;
  f16x8 qf0 = *(const f16x8*)(qp);
  f16x8 qf1 = *(const f16x8*)(qp + 32);

  float m_run = -3e38f, l_run = 0.f;
  f32x4 accO[4];
#pragma unroll
  for (int jo = 0; jo < 4; jo++) accO[jo] = (f32x4){0.f, 0.f, 0.f, 0.f};

  const int nch = (qt >> 1) + 1;  // 128-wide chunks

  f16x8 kreg[4], vreg[4];
  // preload chunk 0
#pragma unroll
  for (int it = 0; it < 4; it++) {
    kreg[it] = *(const f16x8*)(kgbase + (size_t)(it * 32 + krow) * 256);
    vreg[it] = *(const f16x8*)(vgbase + it * 16 * 2048);
  }

  for (int ch = 0; ch < nch; ++ch) {
    const int c0 = ch * 128;
    const bool last = (ch == nch - 1);

    __syncthreads();  // previous chunk's LDS reads complete
#pragma unroll
    for (int it = 0; it < 4; it++) {
      *(f16x8*)(Ks + (it * 32 + krow) * 72 + kcol) = kreg[it];
      *(f16x8*)(Vs + (it * 16 + vrow) * 136 + vcol) = vreg[it];
    }
    __syncthreads();  // staging visible

    // prefetch next chunk into regs (overlaps with compute below)
    if (!last) {
      const int c1 = c0 + 128;
#pragma unroll
      for (int it = 0; it < 4; it++) {
        kreg[it] = *(const f16x8*)(kgbase + (size_t)(c1 + it * 32 + krow) * 256);
        vreg[it] = *(const f16x8*)(vgbase + it * 16 * 2048 + c1);
      }
    }

    // ---- S^T tiles: A = K rows from LDS, B = Q frag ----
    f32x4 st[8];
    __builtin_amdgcn_s_setprio(1);
#pragma unroll
    for (int j = 0; j < 8; j++) {
      const f16* kp = Ks + (j * 16 + lc) * 72 + lr * 8;
      f16x8 ka0 = *(const f16x8*)(kp);
      f16x8 ka1 = *(const f16x8*)(kp + 32);
      f32x4 s = (f32x4){0.f, 0.f, 0.f, 0.f};
      s = __builtin_amdgcn_mfma_f32_16x16x32_f16(ka0, qf0, s, 0, 0, 0);
      s = __builtin_amdgcn_mfma_f32_16x16x32_f16(ka1, qf1, s, 0, 0, 0);
      st[j] = s;
    }
    __builtin_amdgcn_s_setprio(0);

    // ---- causal mask (only last chunk crosses the diagonal) ----
    if (last) {
#pragma unroll
      for (int j = 0; j < 8; j++)
#pragma unroll
        for (int r = 0; r < 4; r++)
          if (c0 + j * 16 + lr * 4 + r > trow) st[j][r] = -3e38f;
    }

    // ---- chunk max: in-lane over 32 regs + 2 shuffles ----
    float mc = -3e38f;
#pragma unroll
    for (int j = 0; j < 8; j++)
      mc = fmaxf(mc, fmaxf(fmaxf(st[j][0], st[j][1]), fmaxf(st[j][2], st[j][3])));
    mc = fmaxf(mc, __shfl_xor(mc, 16));
    mc = fmaxf(mc, __shfl_xor(mc, 32));
    const float mn = fmaxf(m_run, mc);
    const float alpha = __builtin_amdgcn_exp2f(m_run - mn);
    m_run = mn;

    // ---- exp2, packed P^T stores (b64, 2-way = free), in-lane sum ----
    float ls = 0.f;
#pragma unroll
    for (int j = 0; j < 8; j++) {
      f16x4 pv;
#pragma unroll
      for (int r = 0; r < 4; r++) {
        float e = __builtin_amdgcn_exp2f(st[j][r] - mn);
        ls += e;
        pv[r] = (f16)e;
      }
      *(f16x4*)(Pw + lc * 136 + j * 16 + lr * 4) = pv;  // P^T[t=lc][s]
    }
    ls += __shfl_xor(ls, 16);
    ls += __shfl_xor(ls, 32);
    l_run = l_run * alpha + ls;
#pragma unroll
    for (int jo = 0; jo < 4; jo++) accO[jo] *= alpha;

    // ---- O^T += V^T * P^T : A = V^T frags (LDS), B = P^T (wave-private) ----
    __builtin_amdgcn_s_setprio(1);
#pragma unroll
    for (int kkt = 0; kkt < 4; kkt++) {
      f16x8 pb = *(const f16x8*)(Pw + lc * 136 + kkt * 32 + lr * 8);
#pragma unroll
      for (int jo = 0; jo < 4; jo++) {
        f16x8 va = *(const f16x8*)(Vs + (jo * 16 + lc) * 136 + kkt * 32 + lr * 8);
        accO[jo] = __builtin_amdgcn_mfma_f32_16x16x32_f16(va, pb, accO[jo], 0, 0, 0);
      }
    }
    __builtin_amdgcn_s_setprio(0);
  }

  // ---- epilogue: O^T lane holds col t, rows d = jo*16+lr*4+r ----
  const float inv = 1.f / l_run;
#pragma unroll
  for (int jo = 0; jo < 4; jo++) {
    f16x4 hi4, lo4;
#pragma unroll
    for (int r = 0; r < 4; r++) {
      float o = accO[jo][r] * inv;
      f16 hv = (f16)o;
      hi4[r] = hv;
      lo4[r] = (f16)(o - (float)hv);
    }
    const size_t idx = (size_t)trow * 1024 + h * 64 + jo * 16 + lr * 4;
    *(f16x4*)(ahi + idx) = hi4;
    *(f16x4*)(alo + idx) = lo4;
  }
}

// ---------------- silu(g)*u ----------------
__global__ void silu_mul_kernel(const f16* __restrict__ gu, f16* __restrict__ outp, int lgN) {
  const int N = 1 << lgN;
  const size_t i4 = ((size_t)blockIdx.x * 256 + threadIdx.x) * 4;
  const size_t r = i4 >> lgN;
  const int c = (int)(i4 & (N - 1));
  const f16* gp = gu + r * (size_t)(2 * N) + c;
  f16x4 g = *(const f16x4*)gp;
  f16x4 u = *(const f16x4*)(gp + N);
  f16x4 o;
#pragma unroll
  for (int x = 0; x < 4; x++) {
    float gg = (float)g[x], uu = (float)u[x];
    o[x] = (f16)(gg / (1.f + __expf(-gg)) * uu);
  }
  *(f16x4*)(outp + r * (size_t)N + c) = o;
}

// ---------------- final: out += w0*sum_ks eo2[ks][2t] + w1*sum_ks eo2[ks][2t+1]
__global__ void final_add2_kernel(float* __restrict__ outp, const float* __restrict__ eo2,
                                  const float* __restrict__ rw) {
  const size_t i4 = ((size_t)blockIdx.x * 256 + threadIdx.x) * 4;
  const int t = (int)(i4 >> 10);
  const int c = (int)(i4 & 1023);
  const float w0 = rw[2 * t], w1 = rw[2 * t + 1];
  float4 s0 = {0.f, 0.f, 0.f, 0.f}, s1 = {0.f, 0.f, 0.f, 0.f};
#pragma unroll
  for (int ks = 0; ks < 2; ks++) {
    const float* p = eo2 + (size_t)ks * 4096 * 1024;
    float4 a = *(const float4*)(p + (size_t)(2 * t) * 1024 + c);
    float4 b = *(const float4*)(p + (size_t)(2 * t + 1) * 1024 + c);
    s0.x += a.x; s0.y += a.y; s0.z += a.z; s0.w += a.w;
    s1.x += b.x; s1.y += b.y; s1.z += b.z; s1.w += b.w;
  }
  float4 o = *(float4*)(outp + i4);
  o.x += w0 * s0.x + w1 * s1.x;
  o.y += w0 * s0.y + w1 * s1.y;
  o.z += w0 * s0.z + w1 * s1.z;
  o.w += w0 * s0.w + w1 * s1.w;
  *(float4*)(outp + i4) = o;
}

extern "C" void kernel_launch(void* const* d_in, const int* in_sizes, int n_in,
                              void* d_out, int out_size, void* d_ws, size_t ws_size,
                              hipStream_t stream) {
  const int* positions = (const int*)d_in[0];
  const float* hidden = (const float*)d_in[1];
  const float* in_ln = (const float*)d_in[2];
  const float* post_ln = (const float*)d_in[3];
  const float* res_ln = (const float*)d_in[4];
  const float* qkv_w = (const float*)d_in[5];
  const float* o_w = (const float*)d_in[6];
  const float* gate_w = (const float*)d_in[7];
  const float* ws_w = (const float*)d_in[8];
  const float* w2s_w = (const float*)d_in[9];
  const float* w13_w = (const float*)d_in[10];
  const float* w2_w = (const float*)d_in[11];
  float* out = (float*)d_out;

  char* p = (char*)d_ws;
  auto alloc = [&](size_t b) { void* r = (void*)p; p += (b + 255) & ~(size_t)255; return r; };

  f16* wqkv = (f16*)alloc((size_t)1536 * 1024 * 2);
  f16* woh  = (f16*)alloc((size_t)1024 * 1024 * 2);
  f16* wol  = (f16*)alloc((size_t)1024 * 1024 * 2);
  f16* w13  = (f16*)alloc((size_t)2048 * 1024 * 2);
  f16* w2c  = (f16*)alloc((size_t)1024 * 1024 * 2);
  f16* hn   = (f16*)alloc((size_t)2048 * 1024 * 2);
  float* qkvp = (float*)alloc((size_t)2 * 2048 * 1536 * 4);  // qkv split partials
  float2* ptab = (float2*)alloc((size_t)2048 * 32 * 8);      // rope phase table
  f16* qr = (f16*)alloc((size_t)2048 * 1024 * 2);
  f16* kr = (f16*)alloc((size_t)2048 * 256 * 2);
  f16* vt = (f16*)alloc((size_t)256 * 2048 * 2);
  f16* ath = (f16*)alloc((size_t)2048 * 1024 * 2);
  f16* atl = (f16*)alloc((size_t)2048 * 1024 * 2);
  float* opp = (float*)alloc((size_t)2 * 2048 * 1024 * 4);   // o-proj split partials
  float* resA = (float*)alloc((size_t)2048 * 1024 * 4);
  f16* rn = (f16*)alloc((size_t)2048 * 1024 * 2);
  f16* mn = (f16*)alloc((size_t)2048 * 1024 * 2);
  f16* gu13 = (f16*)alloc((size_t)2048 * 2048 * 2);
  f16* act13 = (f16*)alloc((size_t)2048 * 1024 * 2);
  float* w2p = (float*)alloc((size_t)2 * 2048 * 1024 * 4);   // w2 split partials
  f16* actm = (f16*)alloc((size_t)4096 * 2048 * 2);
  float* eo2 = (float*)alloc((size_t)2 * 4096 * 1024 * 4);   // down-proj split partials
  float* rw = (float*)alloc((size_t)4096 * 4);
  int* counts = (int*)alloc(256);
  int* perm = (int*)alloc((size_t)8 * 2048 * 4);

  // weight conversions (ws is re-poisoned before every timed launch)
  // NOTE: MoE weights (ws_w, w2s_w) are now consumed fp32 directly by the GEMMs.
  cvt_f16_kernel<<<dim3(1536 * 1024 / 1024), dim3(256), 0, stream>>>(qkv_w, wqkv);
  cvt_f16_kernel<<<dim3(2048 * 1024 / 1024), dim3(256), 0, stream>>>(w13_w, w13);
  cvt_f16_kernel<<<dim3(1024 * 1024 / 1024), dim3(256), 0, stream>>>(w2_w, w2c);
  cvt_f16x2_kernel<<<dim3(1024 * 1024 / 1024), dim3(256), 0, stream>>>(o_w, woh, wol);
  rope_table_kernel<<<dim3(256), dim3(256), 0, stream>>>(positions, ptab);
  hipMemsetAsync(counts, 0, 256, stream);

  // attention path
  rmsnorm_kernel<<<dim3(512), dim3(256), 0, stream>>>(hidden, in_ln, hn);
  gemm_f16_kernel<0, 64, 2><<<dim3(24, 16, 2), dim3(256), 0, stream>>>(
      hn, wqkv, (void*)qkvp, (const float*)nullptr, 2048, 1536, 1024);
  rope_kernel<<<dim3(3, 2048), dim3(256), 0, stream>>>(qkvp, ptab, qr, kr);
  vtrans_kernel<<<dim3(32, 4), dim3(256), 0, stream>>>(qkvp, vt);
  attn_kernel<<<dim3(32, 16), dim3(256), 0, stream>>>(qr, kr, vt, ath, atl);
  gemm_f16x2_add_kernel<2><<<dim3(16, 16, 2), dim3(256), 0, stream>>>(
      ath, atl, woh, wol, opp, (const float*)nullptr, 2048, 1024, 1024);
  add3_kernel<<<dim3(2048), dim3(256), 0, stream>>>(
      resA, hidden, opp, opp + (size_t)2048 * 1024);

  // fused norms + routing off residual_attn
  rmsnorm_dual_route_kernel<<<dim3(512), dim3(256), 0, stream>>>(
      resA, res_ln, post_ln, gate_w, rn, mn, counts, perm, rw);

  // residual MLP -> d_out holds residual_mlp
  gemm_f16_kernel<2, 64><<<dim3(32, 16), dim3(256), 0, stream>>>(
      rn, w13, (void*)gu13, (const float*)nullptr, 2048, 2048, 1024);
  silu_mul_kernel<<<dim3(2048 * 1024 / 1024), dim3(256), 0, stream>>>(gu13, act13, 10);
  gemm_f16_kernel<0, 64, 2><<<dim3(16, 16, 2), dim3(256), 0, stream>>>(
      act13, w2c, (void*)w2p, (const float*)nullptr, 2048, 1024, 1024);
  add3_kernel<<<dim3(2048), dim3(256), 0, stream>>>(
      out, resA, w2p, w2p + (size_t)2048 * 1024);

  // MoE (top-2 sparse): fp32 weights read directly
  gemm_moe_gated_kernel<<<dim3(32, 16, 8), dim3(256), 0, stream>>>(
      mn, ws_w, actm, perm, counts, 1024, (size_t)4096 * 1024);
  gemm_moe_down_kernel<<<dim3(8, 16, 16), dim3(256), 0, stream>>>(
      actm, w2s_w, eo2, perm, counts, 1024, 2048, (size_t)1024 * 2048);
  final_add2_kernel<<<dim3(2048 * 1024 / 1024), dim3(256), 0, stream>>>(out, eo2, rw);
}